// Round 16
// baseline (86.342 us; speedup 1.0000x reference)
//
#include <hip/hip_runtime.h>

#define BB     4
#define T_IN   12
#define T_OUT  24
#define NNODES 5000
#define CC     32
#define HH     8
#define K1     17
#define O_OUT  12
#define XSTRIDE (NNODES*CC)   // floats per (b,t) plane
#define TPU     (NNODES*16)   // legacy mirror plane (fallback path)

// bf16 x-mirror: xb2[b][node][t][c2] dwords (dword = bf16 ch-pair 2c2,2c2+1)
#define XB2_BN  192               // dwords per (b,node) = 12 t * 16 c2
#define XB2_B   (NNODES*XB2_BN)   // dwords per b
// V j-pair-packed: Vb2[n][q(4)][jp(9)][tq(3)][o(12)] dwords;
// dword = (bf16 V[2jp,t,o] low, bf16 V[2jp+1,t,o] high); jp=8 high half = 0.
#define JP      9
#define VJPD    36                // dwords per (q,jp) block = 3*12
#define VQD     (JP*VJPD)         // 324 dwords per (n,q)
#define VND     (4*VQD)           // 1296 dwords per node

// ---------------- kernel: global max over nearest_dists ----------------
__global__ void max_reduce_kernel(const float* __restrict__ d, int n,
                                  unsigned* __restrict__ out) {
    float m = 0.0f;  // dists >= 0
    for (int i = blockIdx.x * blockDim.x + threadIdx.x; i < n;
         i += gridDim.x * blockDim.x)
        m = fmaxf(m, d[i]);
#pragma unroll
    for (int off = 32; off > 0; off >>= 1)
        m = fmaxf(m, __shfl_down(m, off, 64));
    if ((threadIdx.x & 63) == 0)
        atomicMax(out, __float_as_uint(m));
}

__device__ inline unsigned bf16rne(float f) {
    unsigned u = __float_as_uint(f);
    return (u + 0x7FFFu + ((u >> 16) & 1u)) >> 16;
}

// --- prep4c2: COALESCED copy + mirror (thread-per-float4) ------------------
__global__ void prep4c2_kernel(const float4* __restrict__ x,
                               float4* __restrict__ out,
                               unsigned* __restrict__ xb2d) {
    const int gs = gridDim.x * blockDim.x;
    const int g0 = blockIdx.x * blockDim.x + threadIdx.x;
    const int PLANE4 = NNODES * CC / 4;       // 40000 float4 per (b,t) plane
    const int totalA = BB * T_IN * PLANE4;    // 1,920,000
    for (int i = g0; i < totalA; i += gs) {
        int bt = i / PLANE4;
        int qq = i - bt * PLANE4;
        int b  = bt / T_IN;
        int t  = bt - b * T_IN;
        float4 v = x[i];
        out[((size_t)(b * T_OUT + t)) * PLANE4 + qq] = v;   // coalesced
        int n  = qq >> 3;
        int cq = qq & 7;
        uint2 pk;
        pk.x = bf16rne(v.x) | (bf16rne(v.y) << 16);
        pk.y = bf16rne(v.z) | (bf16rne(v.w) << 16);
        *(uint2*)&xb2d[(((size_t)(b * NNODES + n)) * T_IN + t) * 16 + 2 * cq] = pk;
    }
}

// --- vbuild4: per-node wj (in LDS) + combined V -> global Vb2 -------------
__launch_bounds__(192)
__global__ void vbuild4_kernel(const int* __restrict__ nn,
                               const float* __restrict__ nd,
                               const float* __restrict__ Wsh,
                               const unsigned* __restrict__ maxbits,
                               unsigned* __restrict__ Vb2) {
    __shared__ float wjl[144];   // wj[j(18)][h(8)], j=17 pad
    const int n = blockIdx.x, tid = threadIdx.x;
    if (tid < 144) {
        int j = tid >> 3, h = tid & 7;
        float wv = 0.f;
        if (j < K1) {
            float mx = __uint_as_float(*maxbits);
            float inv_s2 = 4.0f / (mx * mx);      // 1/sigma^2, sigma = mx/2
            float dv = nd[n * K1 + j];
            float lam = (float)(h + 1) * 0.125f;
            wv = expf(-dv * dv * lam * inv_s2);
            if (nn[n * K1 + j] == -1 || wv < 1e-5f) wv = 0.0f;
        }
        wjl[tid] = wv;
    }
    __syncthreads();
    if (tid < 144) {
        const int t = tid / 12;
        const int o = tid - t * 12;
        float Wcol[8];
#pragma unroll
        for (int h = 0; h < 8; ++h) Wcol[h] = Wsh[(t * 8 + h) * 12 + o];
        unsigned* vn = Vb2 + (size_t)n * VND + (t / 3) * VQD + (t % 3) * 12 + o;
#pragma unroll
        for (int jp = 0; jp < JP; ++jp) {
            float4 a0 = *(const float4*)&wjl[jp * 16];
            float4 a1 = *(const float4*)&wjl[jp * 16 + 4];
            float4 b0 = *(const float4*)&wjl[jp * 16 + 8];
            float4 b1 = *(const float4*)&wjl[jp * 16 + 12];
            float wa[8] = {a0.x, a0.y, a0.z, a0.w, a1.x, a1.y, a1.z, a1.w};
            float wb[8] = {b0.x, b0.y, b0.z, b0.w, b1.x, b1.y, b1.z, b1.w};
            float v0 = 0.f, v1 = 0.f;
#pragma unroll
            for (int h = 0; h < 8; ++h) {
                v0 = fmaf(wa[h], Wcol[h], v0);
                v1 = fmaf(wb[h], Wcol[h], v1);
            }
            vn[jp * VJPD] = bf16rne(v0) | (bf16rne(v1) << 16);
        }
    }
}

// --- main13: ASM-FORCED 54-deep gather + SMEM-V hot loop -------------------
struct VBlk { uint4 v[9]; };

__device__ __forceinline__ unsigned u4c(const uint4& u, int i) {
    switch (i) { case 0: return u.x; case 1: return u.y;
                 case 2: return u.z; default: return u.w; }
}

// volatile: keeps program order vs the load blocks and the vmcnt wait
#define DOT2V(ACC, XP, VP) \
    asm volatile("v_dot2_f32_bf16 %0, %1, %2, %0" : "+v"(ACC) : "v"(XP), "s"(VP))

// 18 loads from 6 base addresses (offsets 0/64/128 B = t-rows), one block.
// "=&v" early-clobber: outputs may not alias the address registers.
#define LDBLK(X0_,X1_,X2_,X3_,X4_,X5_,X6_,X7_,X8_,X9_,X10_,X11_,X12_,X13_,X14_,X15_,X16_,X17_, A0_,A1_,A2_,A3_,A4_,A5_) \
    asm volatile( \
        "global_load_dword %0,  %18, off\n\t" \
        "global_load_dword %1,  %18, off offset:64\n\t" \
        "global_load_dword %2,  %18, off offset:128\n\t" \
        "global_load_dword %3,  %19, off\n\t" \
        "global_load_dword %4,  %19, off offset:64\n\t" \
        "global_load_dword %5,  %19, off offset:128\n\t" \
        "global_load_dword %6,  %20, off\n\t" \
        "global_load_dword %7,  %20, off offset:64\n\t" \
        "global_load_dword %8,  %20, off offset:128\n\t" \
        "global_load_dword %9,  %21, off\n\t" \
        "global_load_dword %10, %21, off offset:64\n\t" \
        "global_load_dword %11, %21, off offset:128\n\t" \
        "global_load_dword %12, %22, off\n\t" \
        "global_load_dword %13, %22, off offset:64\n\t" \
        "global_load_dword %14, %22, off offset:128\n\t" \
        "global_load_dword %15, %23, off\n\t" \
        "global_load_dword %16, %23, off offset:64\n\t" \
        "global_load_dword %17, %23, off offset:128" \
        : "=&v"(X0_), "=&v"(X1_), "=&v"(X2_), "=&v"(X3_), "=&v"(X4_),   \
          "=&v"(X5_), "=&v"(X6_), "=&v"(X7_), "=&v"(X8_), "=&v"(X9_),   \
          "=&v"(X10_), "=&v"(X11_), "=&v"(X12_), "=&v"(X13_),           \
          "=&v"(X14_), "=&v"(X15_), "=&v"(X16_), "=&v"(X17_)            \
        : "v"(A0_), "v"(A1_), "v"(A2_), "v"(A3_), "v"(A4_), "v"(A5_))

__launch_bounds__(256)
__global__ void gnn_main13_kernel(const unsigned* __restrict__ xb2,
                                  const unsigned* __restrict__ Vb2,
                                  const int* __restrict__ nn,
                                  const float* __restrict__ bsh,
                                  float* __restrict__ out) {
    __shared__ float pb2[2][24][65];   // 12.48 KB (2-stage reduction)

    const int n    = blockIdx.x;
    const int tid  = threadIdx.x;
    const int q    = __builtin_amdgcn_readfirstlane(tid >> 6);
    const int lane = tid & 63;
    const int bb   = lane >> 4;
    const int c2   = lane & 15;

    int nnv[18];
#pragma unroll
    for (int j = 0; j < K1; ++j) nnv[j] = max(nn[n * K1 + j], 0);  // s_load
    nnv[17] = nnv[16];   // pad pair partner (V high half is 0 there)

    const unsigned* xlane = xb2 + bb * XB2_B + 48 * q + c2;
    const unsigned* vbase = Vb2 + (size_t)n * VND + q * VQD;

    // 18 gather base addresses (one per neighbor slot)
    const unsigned* a0  = xlane + nnv[0]  * XB2_BN;
    const unsigned* a1  = xlane + nnv[1]  * XB2_BN;
    const unsigned* a2  = xlane + nnv[2]  * XB2_BN;
    const unsigned* a3  = xlane + nnv[3]  * XB2_BN;
    const unsigned* a4  = xlane + nnv[4]  * XB2_BN;
    const unsigned* a5  = xlane + nnv[5]  * XB2_BN;
    const unsigned* a6  = xlane + nnv[6]  * XB2_BN;
    const unsigned* a7  = xlane + nnv[7]  * XB2_BN;
    const unsigned* a8  = xlane + nnv[8]  * XB2_BN;
    const unsigned* a9  = xlane + nnv[9]  * XB2_BN;
    const unsigned* a10 = xlane + nnv[10] * XB2_BN;
    const unsigned* a11 = xlane + nnv[11] * XB2_BN;
    const unsigned* a12 = xlane + nnv[12] * XB2_BN;
    const unsigned* a13 = xlane + nnv[13] * XB2_BN;
    const unsigned* a14 = xlane + nnv[14] * XB2_BN;
    const unsigned* a15 = xlane + nnv[15] * XB2_BN;
    const unsigned* a16 = xlane + nnv[16] * XB2_BN;
    const unsigned* a17 = xlane + nnv[17] * XB2_BN;

    // 54 forced-live gather dwords: X<j>_<t> for neighbor j, t-row t
    unsigned X0_0,X0_1,X0_2, X1_0,X1_1,X1_2, X2_0,X2_1,X2_2,
             X3_0,X3_1,X3_2, X4_0,X4_1,X4_2, X5_0,X5_1,X5_2;
    unsigned X6_0,X6_1,X6_2, X7_0,X7_1,X7_2, X8_0,X8_1,X8_2,
             X9_0,X9_1,X9_2, X10_0,X10_1,X10_2, X11_0,X11_1,X11_2;
    unsigned X12_0,X12_1,X12_2, X13_0,X13_1,X13_2, X14_0,X14_1,X14_2,
             X15_0,X15_1,X15_2, X16_0,X16_1,X16_2, X17_0,X17_1,X17_2;

    LDBLK(X0_0,X0_1,X0_2, X1_0,X1_1,X1_2, X2_0,X2_1,X2_2,
          X3_0,X3_1,X3_2, X4_0,X4_1,X4_2, X5_0,X5_1,X5_2,
          a0, a1, a2, a3, a4, a5);
    LDBLK(X6_0,X6_1,X6_2, X7_0,X7_1,X7_2, X8_0,X8_1,X8_2,
          X9_0,X9_1,X9_2, X10_0,X10_1,X10_2, X11_0,X11_1,X11_2,
          a6, a7, a8, a9, a10, a11);
    LDBLK(X12_0,X12_1,X12_2, X13_0,X13_1,X13_2, X14_0,X14_1,X14_2,
          X15_0,X15_1,X15_2, X16_0,X16_1,X16_2, X17_0,X17_1,X17_2,
          a12, a13, a14, a15, a16, a17);

    // V prologue: SMEM loads overlap the 54 in-flight gathers
#define VLOADP(DST, JPI) do {                                                \
        const uint4* vp_ = (const uint4*)(vbase + (JPI) * VJPD);             \
        _Pragma("unroll")                                                    \
        for (int i_ = 0; i_ < 9; ++i_) DST.v[i_] = vp_[i_];                  \
    } while (0)

    VBlk va, vb;
    VLOADP(va, 0);
    VLOADP(vb, 1);

    // drain the asm gathers; fence the scheduler (rule #18)
    asm volatile("s_waitcnt vmcnt(0)" ::: "memory");
    __builtin_amdgcn_sched_barrier(0);

    float pf[24];
#pragma unroll
    for (int i = 0; i < 24; ++i) pf[i] = 0.f;

#define COMPPX(VV, E0, E1, E2, O0, O1, O2) do {                              \
        unsigned xe_[3] = {E0, E1, E2};                                      \
        unsigned xo_[3] = {O0, O1, O2};                                      \
        _Pragma("unroll")                                                    \
        for (int t_ = 0; t_ < 3; ++t_) {                                     \
            unsigned plo_ = __builtin_amdgcn_perm(xe_[t_], xo_[t_],          \
                                                  0x01000504u);              \
            unsigned phi_ = __builtin_amdgcn_perm(xe_[t_], xo_[t_],          \
                                                  0x03020706u);              \
            _Pragma("unroll")                                                \
            for (int o_ = 0; o_ < 12; ++o_) {                                \
                unsigned vp_ = u4c(VV.v[t_ * 3 + (o_ >> 2)], o_ & 3);        \
                DOT2V(pf[o_],      plo_, vp_);                               \
                DOT2V(pf[12 + o_], phi_, vp_);                               \
            }                                                                \
        }                                                                    \
    } while (0)

    // jp=0..8; V double-buffered via SMEM
    COMPPX(va, X0_0,X0_1,X0_2,   X1_0,X1_1,X1_2);   VLOADP(va, 2);
    COMPPX(vb, X2_0,X2_1,X2_2,   X3_0,X3_1,X3_2);   VLOADP(vb, 3);
    COMPPX(va, X4_0,X4_1,X4_2,   X5_0,X5_1,X5_2);   VLOADP(va, 4);
    COMPPX(vb, X6_0,X6_1,X6_2,   X7_0,X7_1,X7_2);   VLOADP(vb, 5);
    COMPPX(va, X8_0,X8_1,X8_2,   X9_0,X9_1,X9_2);   VLOADP(va, 6);
    COMPPX(vb, X10_0,X10_1,X10_2, X11_0,X11_1,X11_2); VLOADP(vb, 7);
    COMPPX(va, X12_0,X12_1,X12_2, X13_0,X13_1,X13_2); VLOADP(va, 8);
    COMPPX(vb, X14_0,X14_1,X14_2, X15_0,X15_1,X15_2);
    COMPPX(va, X16_0,X16_1,X16_2, X17_0,X17_1,X17_2);

#undef VLOADP
#undef COMPPX

    // --- 2-stage cross-wave (q) reduction, bias + swish + store ---
    if (q >= 2) {
#pragma unroll
        for (int i = 0; i < 24; ++i) pb2[q - 2][i][lane] = pf[i];
    }
    __syncthreads();
    if (q < 2) {
#pragma unroll
        for (int i = 0; i < 24; ++i) pf[i] += pb2[q][i][lane];
    }
    if (q == 1) {
#pragma unroll
        for (int i = 0; i < 24; ++i) pb2[1][i][lane] = pf[i];
    }
    __syncthreads();
    if (q == 0) {
        float* ob = out + ((size_t)(bb * T_OUT + T_IN) * NNODES + n) * CC + 2 * c2;
#pragma unroll
        for (int o = 0; o < O_OUT; ++o) {
            float bo = bsh[o];                       // uniform -> s_load
            float v0 = pf[o]      + pb2[1][o][lane]      + bo;
            float v1 = pf[12 + o] + pb2[1][12 + o][lane] + bo;
            float s0 = v0 / (1.f + expf(-0.8f * v0));
            float s1 = v1 / (1.f + expf(-0.8f * v1));
            *(float2*)(ob + (size_t)o * XSTRIDE) = make_float2(s0, s1);
        }
    }
}

// ======================= fallback path (round-3) ==========================
template <int PACK>
__global__ void prep_kernel(const float4* __restrict__ x,
                            float4* __restrict__ out,
                            uint2* __restrict__ xb) {
    const int PLANE4 = NNODES * CC / 4;
    const int total  = BB * T_IN * PLANE4;
    for (int i = blockIdx.x * blockDim.x + threadIdx.x; i < total;
         i += gridDim.x * blockDim.x) {
        int bt = i / PLANE4;
        int qq = i - bt * PLANE4;
        int b  = bt / T_IN;
        int t  = bt - b * T_IN;
        float4 v = x[i];
        out[((size_t)(b * T_OUT + t)) * PLANE4 + qq] = v;
        if (PACK) {
            uint2 pk;
            pk.x = bf16rne(v.x) | (bf16rne(v.y) << 16);
            pk.y = bf16rne(v.z) | (bf16rne(v.w) << 16);
            xb[i] = pk;
        }
    }
}

template <int USEBF>
__launch_bounds__(256)
__global__ void gnn_main_kernel(const float* __restrict__ x,
                                const unsigned* __restrict__ xbu,
                                const int* __restrict__ nn,
                                const float* __restrict__ nd,
                                const float* __restrict__ Wsh,
                                const float* __restrict__ bsh,
                                const unsigned* __restrict__ maxbits,
                                float* __restrict__ out) {
    __shared__ float wl[K1][HH];
    __shared__ float Wl[96][O_OUT];
    __shared__ float bl_s[O_OUT];
    __shared__ int   nnl[K1];

    const int n   = blockIdx.x;
    const int tid = threadIdx.x;
    const int rg  = tid >> 4;
    const int c2  = tid & 15;
    const int b   = rg >> 2;
    const int q   = rg & 3;

    for (int i = tid; i < 288; i += 256)
        ((float4*)Wl)[i] = ((const float4*)Wsh)[i];
    if (tid < O_OUT) bl_s[tid] = bsh[tid];
    if (tid < K1 * HH) {
        int j = tid >> 3, h = tid & 7;
        int v = nn[n * K1 + j];
        float dv = nd[n * K1 + j];
        float mx = __uint_as_float(*maxbits);
        float inv_s2 = 4.0f / (mx * mx);
        float lam = (float)(h + 1) * 0.125f;
        float wv = expf(-dv * dv * lam * inv_s2);
        if (v == -1 || wv < 1e-5f) wv = 0.0f;
        wl[j][h] = wv;
    }
    if (tid < K1) nnl[tid] = max(nn[n * K1 + tid], 0);
    __syncthreads();

    float acc[3][2][8];
#pragma unroll
    for (int k = 0; k < 3; ++k)
#pragma unroll
        for (int cc = 0; cc < 2; ++cc)
#pragma unroll
            for (int h = 0; h < 8; ++h) acc[k][cc][h] = 0.f;

    if (USEBF) {
        const unsigned* xbase = xbu + (b * T_IN + 3 * q) * TPU + c2;
        unsigned ua0, ua1, ua2, ub0, ub1, ub2;
#define LOADB(u0, u1, u2, J) do {                                            \
        int idx_ = __builtin_amdgcn_readfirstlane(nnl[(J)]);                 \
        const unsigned* bp_ = xbase + idx_ * 16;                             \
        u0 = bp_[0]; u1 = bp_[TPU]; u2 = bp_[2 * TPU];                       \
    } while (0)
#define COMPB(u0, u1, u2, J) do {                                            \
        float4 wA_ = *(const float4*)&wl[(J)][0];                            \
        float4 wB_ = *(const float4*)&wl[(J)][4];                            \
        float wv_[8] = {wA_.x, wA_.y, wA_.z, wA_.w,                          \
                        wB_.x, wB_.y, wB_.z, wB_.w};                         \
        float xl_[3] = {__uint_as_float(u0 << 16),                           \
                        __uint_as_float(u1 << 16),                           \
                        __uint_as_float(u2 << 16)};                          \
        float xh_[3] = {__uint_as_float(u0 & 0xffff0000u),                   \
                        __uint_as_float(u1 & 0xffff0000u),                   \
                        __uint_as_float(u2 & 0xffff0000u)};                  \
        _Pragma("unroll")                                                    \
        for (int k_ = 0; k_ < 3; ++k_)                                       \
            _Pragma("unroll")                                                \
            for (int h_ = 0; h_ < 8; ++h_) {                                 \
                acc[k_][0][h_] = fmaf(wv_[h_], xl_[k_], acc[k_][0][h_]);     \
                acc[k_][1][h_] = fmaf(wv_[h_], xh_[k_], acc[k_][1][h_]);     \
            }                                                                \
    } while (0)
        LOADB(ua0, ua1, ua2, 0);
#pragma unroll 1
        for (int jj = 0; jj < 8; ++jj) {
            LOADB(ub0, ub1, ub2, 2 * jj + 1);
            COMPB(ua0, ua1, ua2, 2 * jj);
            LOADB(ua0, ua1, ua2, 2 * jj + 2);
            COMPB(ub0, ub1, ub2, 2 * jj + 1);
        }
        COMPB(ua0, ua1, ua2, 16);
#undef LOADB
#undef COMPB
    } else {
        const float* xbase = x + (b * T_IN + 3 * q) * XSTRIDE + 2 * c2;
        float2 xa0, xa1, xa2, xb0, xb1, xb2;
#define LOADJ(v0, v1, v2, J) do {                                            \
        int idx_ = __builtin_amdgcn_readfirstlane(nnl[(J)]);                 \
        const float* bp_ = xbase + idx_ * CC;                                \
        v0 = *(const float2*)(bp_);                                          \
        v1 = *(const float2*)(bp_ + XSTRIDE);                                \
        v2 = *(const float2*)(bp_ + 2 * XSTRIDE);                            \
    } while (0)
#define COMPJ(v0, v1, v2, J) do {                                            \
        float4 wA_ = *(const float4*)&wl[(J)][0];                            \
        float4 wB_ = *(const float4*)&wl[(J)][4];                            \
        float wv_[8] = {wA_.x, wA_.y, wA_.z, wA_.w,                          \
                        wB_.x, wB_.y, wB_.z, wB_.w};                         \
        float xv_[3][2] = {{v0.x, v0.y}, {v1.x, v1.y}, {v2.x, v2.y}};        \
        _Pragma("unroll")                                                    \
        for (int k_ = 0; k_ < 3; ++k_)                                       \
            _Pragma("unroll")                                                \
            for (int cc_ = 0; cc_ < 2; ++cc_)                                \
                _Pragma("unroll")                                            \
                for (int h_ = 0; h_ < 8; ++h_)                               \
                    acc[k_][cc_][h_] =                                       \
                        fmaf(wv_[h_], xv_[k_][cc_], acc[k_][cc_][h_]);       \
    } while (0)
        LOADJ(xa0, xa1, xa2, 0);
#pragma unroll 1
        for (int jj = 0; jj < 8; ++jj) {
            LOADJ(xb0, xb1, xb2, 2 * jj + 1);
            COMPJ(xa0, xa1, xa2, 2 * jj);
            LOADJ(xa0, xa1, xa2, 2 * jj + 2);
            COMPJ(xb0, xb1, xb2, 2 * jj + 1);
        }
        COMPJ(xa0, xa1, xa2, 16);
#undef LOADJ
#undef COMPJ
    }

    float p[2][O_OUT];
#pragma unroll
    for (int o = 0; o < O_OUT; ++o) { p[0][o] = 0.f; p[1][o] = 0.f; }
#pragma unroll
    for (int k = 0; k < 3; ++k) {
#pragma unroll
        for (int h = 0; h < 8; ++h) {
            int row = (3 * q + k) * 8 + h;
            const float4* wr = (const float4*)&Wl[row][0];
            float4 w0 = wr[0], w1 = wr[1], w2 = wr[2];
            float wrow[12] = {w0.x, w0.y, w0.z, w0.w,
                              w1.x, w1.y, w1.z, w1.w,
                              w2.x, w2.y, w2.z, w2.w};
            float a0 = acc[k][0][h], a1 = acc[k][1][h];
#pragma unroll
            for (int o = 0; o < O_OUT; ++o) {
                p[0][o] = fmaf(a0, wrow[o], p[0][o]);
                p[1][o] = fmaf(a1, wrow[o], p[1][o]);
            }
        }
    }
#pragma unroll
    for (int cc = 0; cc < 2; ++cc)
#pragma unroll
        for (int o = 0; o < O_OUT; ++o) {
            float v = p[cc][o];
            v += __shfl_xor(v, 16, 64);
            v += __shfl_xor(v, 32, 64);
            p[cc][o] = v;
        }
    if (q == 0) {
        float* ob = out + ((size_t)(b * T_OUT + T_IN) * NNODES + n) * CC + 2 * c2;
#pragma unroll
        for (int o = 0; o < O_OUT; ++o) {
            float v0 = p[0][o] + bl_s[o];
            float v1 = p[1][o] + bl_s[o];
            float s0 = v0 / (1.f + expf(-0.8f * v0));
            float s1 = v1 / (1.f + expf(-0.8f * v1));
            *(float2*)(ob + (size_t)o * XSTRIDE) = make_float2(s0, s1);
        }
    }
}

extern "C" void kernel_launch(void* const* d_in, const int* in_sizes, int n_in,
                              void* d_out, int out_size, void* d_ws, size_t ws_size,
                              hipStream_t stream) {
    const float* x   = (const float*)d_in[0];
    const int*   nn  = (const int*)d_in[1];
    const float* nd  = (const float*)d_in[2];
    const float* Wsh = (const float*)d_in[3];
    const float* bsh = (const float*)d_in[4];
    float* out = (float*)d_out;

    unsigned* maxbits = (unsigned*)d_ws;
    hipMemsetAsync(d_ws, 0, sizeof(unsigned), stream);
    max_reduce_kernel<<<128, 256, 0, stream>>>(nd, NNODES * K1, maxbits);

    const size_t xb2_off = 1024;
    const size_t xb2_sz  = (size_t)BB * NNODES * T_IN * 16 * 4;   // 15,360,000
    const size_t vb_off  = xb2_off + xb2_sz;                      // 16B aligned
    const size_t vb_sz   = (size_t)NNODES * VND * 4;              // 25,920,000
    const size_t need2   = vb_off + vb_sz;                        // ~41.3 MB

    if (ws_size >= need2) {
        unsigned* xb2d = (unsigned*)((char*)d_ws + xb2_off);
        unsigned* Vb2  = (unsigned*)((char*)d_ws + vb_off);

        prep4c2_kernel<<<2048, 256, 0, stream>>>(
            (const float4*)x, (float4*)out, xb2d);
        vbuild4_kernel<<<NNODES, 192, 0, stream>>>(nn, nd, Wsh, maxbits, Vb2);
        gnn_main13_kernel<<<NNODES, 256, 0, stream>>>(
            xb2d, Vb2, nn, bsh, out);
    } else {
        unsigned* xbu = (unsigned*)((char*)d_ws + 256);
        const size_t need1 = 256 + (size_t)BB * T_IN * NNODES * CC * 2;
        if (ws_size >= need1) {
            prep_kernel<1><<<2048, 256, 0, stream>>>((const float4*)x,
                                                     (float4*)out, (uint2*)xbu);
            gnn_main_kernel<1><<<NNODES, 256, 0, stream>>>(x, xbu, nn, nd, Wsh,
                                                           bsh, maxbits, out);
        } else {
            prep_kernel<0><<<2048, 256, 0, stream>>>((const float4*)x,
                                                     (float4*)out, (uint2*)xbu);
            gnn_main_kernel<0><<<NNODES, 256, 0, stream>>>(x, xbu, nn, nd, Wsh,
                                                           bsh, maxbits, out);
        }
    }
}

// Round 17
// 78.713 us; speedup vs baseline: 1.0969x; 1.0969x over previous
//
#include <hip/hip_runtime.h>

#define BB     4
#define T_IN   12
#define T_OUT  24
#define NNODES 5000
#define CC     32
#define HH     8
#define K1     17
#define O_OUT  12
#define XSTRIDE (NNODES*CC)   // floats per (b,t) plane
#define TPU     (NNODES*16)   // legacy mirror plane (fallback path)

// bf16 x-mirror: xb2[b][node][t][c2] dwords (dword = bf16 ch-pair 2c2,2c2+1)
#define XB2_BN  192               // dwords per (b,node) = 12 t * 16 c2
#define XB2_B   (NNODES*XB2_BN)   // dwords per b
// V j-pair-packed (in LDS): [q(4)][jp(9)][t(3)][o(12)] dwords;
// dword = (bf16 V[2jp,t,o] low, bf16 V[2jp+1,t,o] high); jp=8 high half = 0.
#define JP      9
#define VJPD    36                // dwords per (q,jp) block = 3*12
#define VQD     (JP*VJPD)         // 324 dwords per q
#define VND     (4*VQD)           // 1296 dwords total
#define WJN     144               // wj floats per node: [j(18)][h(8)], j=17 pad

// ---------------- kernel: global max over nearest_dists ----------------
__global__ void max_reduce_kernel(const float* __restrict__ d, int n,
                                  unsigned* __restrict__ out) {
    float m = 0.0f;  // dists >= 0
    for (int i = blockIdx.x * blockDim.x + threadIdx.x; i < n;
         i += gridDim.x * blockDim.x)
        m = fmaxf(m, d[i]);
#pragma unroll
    for (int off = 32; off > 0; off >>= 1)
        m = fmaxf(m, __shfl_down(m, off, 64));
    if ((threadIdx.x & 63) == 0)
        atomicMax(out, __float_as_uint(m));
}

__device__ inline unsigned bf16rne(float f) {
    unsigned u = __float_as_uint(f);
    return (u + 0x7FFFu + ((u >> 16) & 1u)) >> 16;
}

// --- prep4c: COALESCED copy + mirror (thread-per-float4) + wj table -------
__global__ void prep4c_kernel(const float4* __restrict__ x,
                              float4* __restrict__ out,
                              unsigned* __restrict__ xb2d,   // dword view
                              const int* __restrict__ nn,
                              const float* __restrict__ nd,
                              const unsigned* __restrict__ maxbits,
                              float* __restrict__ wjg) {
    const int gs = gridDim.x * blockDim.x;
    const int g0 = blockIdx.x * blockDim.x + threadIdx.x;

    // ---- A: copy x -> out[:, :T_IN] + bf16 mirror, fully coalesced ----
    const int PLANE4 = NNODES * CC / 4;       // 40000 float4 per (b,t) plane
    const int totalA = BB * T_IN * PLANE4;    // 1,920,000
    for (int i = g0; i < totalA; i += gs) {
        int bt = i / PLANE4;
        int qq = i - bt * PLANE4;
        int b  = bt / T_IN;
        int t  = bt - b * T_IN;
        float4 v = x[i];
        out[((size_t)(b * T_OUT + t)) * PLANE4 + qq] = v;   // coalesced
        // mirror: float4 = channels 4cq..4cq+3 of node n -> c2 = 2cq, 2cq+1
        int n  = qq >> 3;
        int cq = qq & 7;
        uint2 pk;
        pk.x = bf16rne(v.x) | (bf16rne(v.y) << 16);
        pk.y = bf16rne(v.z) | (bf16rne(v.w) << 16);
        // dword offset ((b*NNODES+n)*T_IN+t)*16 + 2cq  (8B aligned)
        *(uint2*)&xb2d[(((size_t)(b * NNODES + n)) * T_IN + t) * 16 + 2 * cq] = pk;
    }

    // ---- B: wj table (GCN weights) ----
    float mx = __uint_as_float(*maxbits);
    float inv_s2 = 4.0f / (mx * mx);          // 1/sigma^2, sigma = mx/2
    const int totalB = NNODES * WJN;
    for (int i = g0; i < totalB; i += gs) {
        int n = i / WJN;
        int r = i - n * WJN;
        int j = r >> 3, h = r & 7;
        float wv = 0.f;
        if (j < K1) {
            float dv = nd[n * K1 + j];
            float lam = (float)(h + 1) * 0.125f;
            wv = expf(-dv * dv * lam * inv_s2);
            if (nn[n * K1 + j] == -1 || wv < 1e-5f) wv = 0.0f;
        }
        wjg[i] = wv;
    }
}

// ------- main7: dot2 j-pairs, V computed in-block to LDS, 2-stage reduce ---
struct VBlk { uint4 v[9]; };

__device__ __forceinline__ unsigned u4c(const uint4& u, int i) {
    switch (i) { case 0: return u.x; case 1: return u.y;
                 case 2: return u.z; default: return u.w; }
}

#define DOT2(ACC, XP, VP) \
    asm("v_dot2_f32_bf16 %0, %1, %2, %0" : "+v"(ACC) : "v"(XP), "v"(VP))

__launch_bounds__(256)
__global__ void gnn_main7_kernel(const unsigned* __restrict__ xb2,
                                 const float* __restrict__ wjg,
                                 const float* __restrict__ Wsh,
                                 const int* __restrict__ nn,
                                 const float* __restrict__ bsh,
                                 float* __restrict__ out) {
    __shared__ float pb2[2][24][65];   // 12.48 KB (2-stage reduction)
    __shared__ unsigned Vl[VND];       // 5.18 KB combined-weight table
    __shared__ float bl[O_OUT];

    const int n    = blockIdx.x;
    const int tid  = threadIdx.x;
    const int q    = __builtin_amdgcn_readfirstlane(tid >> 6);
    const int lane = tid & 63;
    const int bb   = lane >> 4;
    const int c2   = lane & 15;

    if (tid < O_OUT) bl[tid] = bsh[tid];

    int nnv[18];
#pragma unroll
    for (int j = 0; j < K1; ++j) nnv[j] = max(nn[n * K1 + j], 0);
    nnv[17] = nnv[16];   // pad pair partner (V high half is 0 there)

    const unsigned* xlane = xb2 + bb * XB2_B + 48 * q + c2;

#define XLOADP(E0, E1, E2, O0, O1, O2, JPI) do {                             \
        const unsigned* xe_ = xlane + nnv[2 * (JPI)] * XB2_BN;               \
        const unsigned* xo_ = xlane + nnv[2 * (JPI) + 1] * XB2_BN;           \
        E0 = xe_[0]; E1 = xe_[16]; E2 = xe_[32];                             \
        O0 = xo_[0]; O1 = xo_[16]; O2 = xo_[32];                             \
    } while (0)

    unsigned e00, e01, e02, o00, o01, o02;   // X buf 0
    unsigned e10, e11, e12, o10, o11, o12;   // X buf 1
    unsigned e20, e21, e22, o20, o21, o22;   // X buf 2

    // issue first gathers early (long-latency, overlap V-compute)
    XLOADP(e00, e01, e02, o00, o01, o02, 0);
    XLOADP(e10, e11, e12, o10, o11, o12, 1);

    // ---- V-compute phase: V[q'][jp][t'][o] from wj (s_load) and W ----
    {
        const int t = tid / 12;                 // 0..11 valid for tid<144
        const int o = tid - t * 12;
        float Wcol[8];
        if (tid < 144) {
#pragma unroll
            for (int h = 0; h < 8; ++h) Wcol[h] = Wsh[(t * 8 + h) * 12 + o];
        }
        const float* wp = wjg + n * WJN;        // wave-uniform base
        const int vi = (t / 3) * VQD + (t % 3) * 12 + o;
#pragma unroll
        for (int jp = 0; jp < JP; ++jp) {
            float wa[16];
#pragma unroll
            for (int h = 0; h < 16; ++h) wa[h] = wp[jp * 16 + h];  // s_load
            if (tid < 144) {
                float v0 = 0.f, v1 = 0.f;
#pragma unroll
                for (int h = 0; h < 8; ++h) {
                    v0 = fmaf(wa[h],     Wcol[h], v0);
                    v1 = fmaf(wa[8 + h], Wcol[h], v1);
                }
                Vl[vi + jp * VJPD] = bf16rne(v0) | (bf16rne(v1) << 16);
            }
        }
    }

    float pf[24];
#pragma unroll
    for (int i = 0; i < 24; ++i) pf[i] = 0.f;

    __syncthreads();   // Vl ready

#define VLOADP(DST, JPI) do {                                                \
        const uint4* vp_ = (const uint4*)&Vl[q * VQD + (JPI) * VJPD];        \
        _Pragma("unroll")                                                    \
        for (int i_ = 0; i_ < 9; ++i_) DST.v[i_] = vp_[i_];                  \
    } while (0)

#define COMPP(VV, E0, E1, E2, O0, O1, O2) do {                               \
        unsigned xe_[3] = {E0, E1, E2};                                      \
        unsigned xo_[3] = {O0, O1, O2};                                      \
        _Pragma("unroll")                                                    \
        for (int t_ = 0; t_ < 3; ++t_) {                                     \
            unsigned plo_ = __builtin_amdgcn_perm(xe_[t_], xo_[t_],          \
                                                  0x01000504u);              \
            unsigned phi_ = __builtin_amdgcn_perm(xe_[t_], xo_[t_],          \
                                                  0x03020706u);              \
            _Pragma("unroll")                                                \
            for (int o_ = 0; o_ < 12; ++o_) {                                \
                unsigned vp_ = u4c(VV.v[t_ * 3 + (o_ >> 2)], o_ & 3);        \
                DOT2(pf[o_],      plo_, vp_);                                \
                DOT2(pf[12 + o_], phi_, vp_);                                \
            }                                                                \
        }                                                                    \
    } while (0)

    VBlk va, vb;
    VLOADP(va, 0);
    VLOADP(vb, 1);
    // jp=0
    XLOADP(e20, e21, e22, o20, o21, o22, 2);
    COMPP(va, e00, e01, e02, o00, o01, o02);
    VLOADP(va, 2);
    // jp=1
    XLOADP(e00, e01, e02, o00, o01, o02, 3);
    COMPP(vb, e10, e11, e12, o10, o11, o12);
    VLOADP(vb, 3);
    // jp=2
    XLOADP(e10, e11, e12, o10, o11, o12, 4);
    COMPP(va, e20, e21, e22, o20, o21, o22);
    VLOADP(va, 4);
    // jp=3
    XLOADP(e20, e21, e22, o20, o21, o22, 5);
    COMPP(vb, e00, e01, e02, o00, o01, o02);
    VLOADP(vb, 5);
    // jp=4
    XLOADP(e00, e01, e02, o00, o01, o02, 6);
    COMPP(va, e10, e11, e12, o10, o11, o12);
    VLOADP(va, 6);
    // jp=5
    XLOADP(e10, e11, e12, o10, o11, o12, 7);
    COMPP(vb, e20, e21, e22, o20, o21, o22);
    VLOADP(vb, 7);
    // jp=6
    XLOADP(e20, e21, e22, o20, o21, o22, 8);
    COMPP(va, e00, e01, e02, o00, o01, o02);
    VLOADP(va, 8);
    // jp=7
    COMPP(vb, e10, e11, e12, o10, o11, o12);
    // jp=8
    COMPP(va, e20, e21, e22, o20, o21, o22);

#undef VLOADP
#undef XLOADP
#undef COMPP

    // --- 2-stage cross-wave (q) reduction, bias + swish + store ---
    if (q >= 2) {
#pragma unroll
        for (int i = 0; i < 24; ++i) pb2[q - 2][i][lane] = pf[i];
    }
    __syncthreads();
    if (q < 2) {
#pragma unroll
        for (int i = 0; i < 24; ++i) pf[i] += pb2[q][i][lane];
    }
    if (q == 1) {
#pragma unroll
        for (int i = 0; i < 24; ++i) pb2[1][i][lane] = pf[i];
    }
    __syncthreads();
    if (q == 0) {
        float* ob = out + ((size_t)(bb * T_OUT + T_IN) * NNODES + n) * CC + 2 * c2;
#pragma unroll
        for (int o = 0; o < O_OUT; ++o) {
            float v0 = pf[o]      + pb2[1][o][lane]      + bl[o];
            float v1 = pf[12 + o] + pb2[1][12 + o][lane] + bl[o];
            float s0 = v0 / (1.f + expf(-0.8f * v0));
            float s1 = v1 / (1.f + expf(-0.8f * v1));
            *(float2*)(ob + (size_t)o * XSTRIDE) = make_float2(s0, s1);
        }
    }
}

// ======================= fallback path (round-3) ==========================
template <int PACK>
__global__ void prep_kernel(const float4* __restrict__ x,
                            float4* __restrict__ out,
                            uint2* __restrict__ xb) {
    const int PLANE4 = NNODES * CC / 4;
    const int total  = BB * T_IN * PLANE4;
    for (int i = blockIdx.x * blockDim.x + threadIdx.x; i < total;
         i += gridDim.x * blockDim.x) {
        int bt = i / PLANE4;
        int qq = i - bt * PLANE4;
        int b  = bt / T_IN;
        int t  = bt - b * T_IN;
        float4 v = x[i];
        out[((size_t)(b * T_OUT + t)) * PLANE4 + qq] = v;
        if (PACK) {
            uint2 pk;
            pk.x = bf16rne(v.x) | (bf16rne(v.y) << 16);
            pk.y = bf16rne(v.z) | (bf16rne(v.w) << 16);
            xb[i] = pk;
        }
    }
}

template <int USEBF>
__launch_bounds__(256)
__global__ void gnn_main_kernel(const float* __restrict__ x,
                                const unsigned* __restrict__ xbu,
                                const int* __restrict__ nn,
                                const float* __restrict__ nd,
                                const float* __restrict__ Wsh,
                                const float* __restrict__ bsh,
                                const unsigned* __restrict__ maxbits,
                                float* __restrict__ out) {
    __shared__ float wl[K1][HH];
    __shared__ float Wl[96][O_OUT];
    __shared__ float bl_s[O_OUT];
    __shared__ int   nnl[K1];

    const int n   = blockIdx.x;
    const int tid = threadIdx.x;
    const int rg  = tid >> 4;
    const int c2  = tid & 15;
    const int b   = rg >> 2;
    const int q   = rg & 3;

    for (int i = tid; i < 288; i += 256)
        ((float4*)Wl)[i] = ((const float4*)Wsh)[i];
    if (tid < O_OUT) bl_s[tid] = bsh[tid];
    if (tid < K1 * HH) {
        int j = tid >> 3, h = tid & 7;
        int v = nn[n * K1 + j];
        float dv = nd[n * K1 + j];
        float mx = __uint_as_float(*maxbits);
        float inv_s2 = 4.0f / (mx * mx);
        float lam = (float)(h + 1) * 0.125f;
        float wv = expf(-dv * dv * lam * inv_s2);
        if (v == -1 || wv < 1e-5f) wv = 0.0f;
        wl[j][h] = wv;
    }
    if (tid < K1) nnl[tid] = max(nn[n * K1 + tid], 0);
    __syncthreads();

    float acc[3][2][8];
#pragma unroll
    for (int k = 0; k < 3; ++k)
#pragma unroll
        for (int cc = 0; cc < 2; ++cc)
#pragma unroll
            for (int h = 0; h < 8; ++h) acc[k][cc][h] = 0.f;

    if (USEBF) {
        const unsigned* xbase = xbu + (b * T_IN + 3 * q) * TPU + c2;
        unsigned ua0, ua1, ua2, ub0, ub1, ub2;
#define LOADB(u0, u1, u2, J) do {                                            \
        int idx_ = __builtin_amdgcn_readfirstlane(nnl[(J)]);                 \
        const unsigned* bp_ = xbase + idx_ * 16;                             \
        u0 = bp_[0]; u1 = bp_[TPU]; u2 = bp_[2 * TPU];                       \
    } while (0)
#define COMPB(u0, u1, u2, J) do {                                            \
        float4 wA_ = *(const float4*)&wl[(J)][0];                            \
        float4 wB_ = *(const float4*)&wl[(J)][4];                            \
        float wv_[8] = {wA_.x, wA_.y, wA_.z, wA_.w,                          \
                        wB_.x, wB_.y, wB_.z, wB_.w};                         \
        float xl_[3] = {__uint_as_float(u0 << 16),                           \
                        __uint_as_float(u1 << 16),                           \
                        __uint_as_float(u2 << 16)};                          \
        float xh_[3] = {__uint_as_float(u0 & 0xffff0000u),                   \
                        __uint_as_float(u1 & 0xffff0000u),                   \
                        __uint_as_float(u2 & 0xffff0000u)};                  \
        _Pragma("unroll")                                                    \
        for (int k_ = 0; k_ < 3; ++k_)                                       \
            _Pragma("unroll")                                                \
            for (int h_ = 0; h_ < 8; ++h_) {                                 \
                acc[k_][0][h_] = fmaf(wv_[h_], xl_[k_], acc[k_][0][h_]);     \
                acc[k_][1][h_] = fmaf(wv_[h_], xh_[k_], acc[k_][1][h_]);     \
            }                                                                \
    } while (0)
        LOADB(ua0, ua1, ua2, 0);
#pragma unroll 1
        for (int jj = 0; jj < 8; ++jj) {
            LOADB(ub0, ub1, ub2, 2 * jj + 1);
            COMPB(ua0, ua1, ua2, 2 * jj);
            LOADB(ua0, ua1, ua2, 2 * jj + 2);
            COMPB(ub0, ub1, ub2, 2 * jj + 1);
        }
        COMPB(ua0, ua1, ua2, 16);
#undef LOADB
#undef COMPB
    } else {
        const float* xbase = x + (b * T_IN + 3 * q) * XSTRIDE + 2 * c2;
        float2 xa0, xa1, xa2, xb0, xb1, xb2;
#define LOADJ(v0, v1, v2, J) do {                                            \
        int idx_ = __builtin_amdgcn_readfirstlane(nnl[(J)]);                 \
        const float* bp_ = xbase + idx_ * CC;                                \
        v0 = *(const float2*)(bp_);                                          \
        v1 = *(const float2*)(bp_ + XSTRIDE);                                \
        v2 = *(const float2*)(bp_ + 2 * XSTRIDE);                            \
    } while (0)
#define COMPJ(v0, v1, v2, J) do {                                            \
        float4 wA_ = *(const float4*)&wl[(J)][0];                            \
        float4 wB_ = *(const float4*)&wl[(J)][4];                            \
        float wv_[8] = {wA_.x, wA_.y, wA_.z, wA_.w,                          \
                        wB_.x, wB_.y, wB_.z, wB_.w};                         \
        float xv_[3][2] = {{v0.x, v0.y}, {v1.x, v1.y}, {v2.x, v2.y}};        \
        _Pragma("unroll")                                                    \
        for (int k_ = 0; k_ < 3; ++k_)                                       \
            _Pragma("unroll")                                                \
            for (int cc_ = 0; cc_ < 2; ++cc_)                                \
                _Pragma("unroll")                                            \
                for (int h_ = 0; h_ < 8; ++h_)                               \
                    acc[k_][cc_][h_] =                                       \
                        fmaf(wv_[h_], xv_[k_][cc_], acc[k_][cc_][h_]);       \
    } while (0)
        LOADJ(xa0, xa1, xa2, 0);
#pragma unroll 1
        for (int jj = 0; jj < 8; ++jj) {
            LOADJ(xb0, xb1, xb2, 2 * jj + 1);
            COMPJ(xa0, xa1, xa2, 2 * jj);
            LOADJ(xa0, xa1, xa2, 2 * jj + 2);
            COMPJ(xb0, xb1, xb2, 2 * jj + 1);
        }
        COMPJ(xa0, xa1, xa2, 16);
#undef LOADJ
#undef COMPJ
    }

    float p[2][O_OUT];
#pragma unroll
    for (int o = 0; o < O_OUT; ++o) { p[0][o] = 0.f; p[1][o] = 0.f; }
#pragma unroll
    for (int k = 0; k < 3; ++k) {
#pragma unroll
        for (int h = 0; h < 8; ++h) {
            int row = (3 * q + k) * 8 + h;
            const float4* wr = (const float4*)&Wl[row][0];
            float4 w0 = wr[0], w1 = wr[1], w2 = wr[2];
            float wrow[12] = {w0.x, w0.y, w0.z, w0.w,
                              w1.x, w1.y, w1.z, w1.w,
                              w2.x, w2.y, w2.z, w2.w};
            float a0 = acc[k][0][h], a1 = acc[k][1][h];
#pragma unroll
            for (int o = 0; o < O_OUT; ++o) {
                p[0][o] = fmaf(a0, wrow[o], p[0][o]);
                p[1][o] = fmaf(a1, wrow[o], p[1][o]);
            }
        }
    }
#pragma unroll
    for (int cc = 0; cc < 2; ++cc)
#pragma unroll
        for (int o = 0; o < O_OUT; ++o) {
            float v = p[cc][o];
            v += __shfl_xor(v, 16, 64);
            v += __shfl_xor(v, 32, 64);
            p[cc][o] = v;
        }
    if (q == 0) {
        float* ob = out + ((size_t)(b * T_OUT + T_IN) * NNODES + n) * CC + 2 * c2;
#pragma unroll
        for (int o = 0; o < O_OUT; ++o) {
            float v0 = p[0][o] + bl_s[o];
            float v1 = p[1][o] + bl_s[o];
            float s0 = v0 / (1.f + expf(-0.8f * v0));
            float s1 = v1 / (1.f + expf(-0.8f * v1));
            *(float2*)(ob + (size_t)o * XSTRIDE) = make_float2(s0, s1);
        }
    }
}

extern "C" void kernel_launch(void* const* d_in, const int* in_sizes, int n_in,
                              void* d_out, int out_size, void* d_ws, size_t ws_size,
                              hipStream_t stream) {
    const float* x   = (const float*)d_in[0];
    const int*   nn  = (const int*)d_in[1];
    const float* nd  = (const float*)d_in[2];
    const float* Wsh = (const float*)d_in[3];
    const float* bsh = (const float*)d_in[4];
    float* out = (float*)d_out;

    unsigned* maxbits = (unsigned*)d_ws;
    hipMemsetAsync(d_ws, 0, sizeof(unsigned), stream);
    max_reduce_kernel<<<128, 256, 0, stream>>>(nd, NNODES * K1, maxbits);

    const size_t wjg_off = 1024;
    const size_t wjg_sz  = (size_t)NNODES * WJN * 4;              // 2,880,000
    const size_t xb2_off = wjg_off + wjg_sz;                      // 16B aligned
    const size_t xb2_sz  = (size_t)BB * NNODES * T_IN * 16 * 4;   // 15,360,000
    const size_t need2   = xb2_off + xb2_sz;                      // ~18.2 MB

    if (ws_size >= need2) {
        float*    wjg  = (float*)((char*)d_ws + wjg_off);
        unsigned* xb2d = (unsigned*)((char*)d_ws + xb2_off);

        prep4c_kernel<<<2048, 256, 0, stream>>>(
            (const float4*)x, (float4*)out, xb2d, nn, nd, maxbits, wjg);
        gnn_main7_kernel<<<NNODES, 256, 0, stream>>>(
            xb2d, wjg, Wsh, nn, bsh, out);
    } else {
        unsigned* xbu = (unsigned*)((char*)d_ws + 256);
        const size_t need1 = 256 + (size_t)BB * T_IN * NNODES * CC * 2;
        if (ws_size >= need1) {
            prep_kernel<1><<<2048, 256, 0, stream>>>((const float4*)x,
                                                     (float4*)out, (uint2*)xbu);
            gnn_main_kernel<1><<<NNODES, 256, 0, stream>>>(x, xbu, nn, nd, Wsh,
                                                           bsh, maxbits, out);
        } else {
            prep_kernel<0><<<2048, 256, 0, stream>>>((const float4*)x,
                                                     (float4*)out, (uint2*)xbu);
            gnn_main_kernel<0><<<NNODES, 256, 0, stream>>>(x, xbu, nn, nd, Wsh,
                                                           bsh, maxbits, out);
        }
    }
}